// Round 1
// baseline (249.485 us; speedup 1.0000x reference)
//
#include <hip/hip_runtime.h>
#include <stdint.h>

#define NSUB 16

typedef short bf16x8 __attribute__((ext_vector_type(8)));
typedef float f32x4  __attribute__((ext_vector_type(4)));
typedef unsigned int u32x4 __attribute__((ext_vector_type(4)));

__device__ __forceinline__ float gelu_exact(float x){
  return 0.5f * x * (1.0f + erff(x * 0.70710678118654752440f));
}

__device__ __forceinline__ unsigned short f2bf(float f){
  union { float f; uint32_t u; } v; v.f = f;
  uint32_t u = v.u;
  return (unsigned short)((u + 0x7FFFu + ((u >> 16) & 1u)) >> 16);
}

// ---------------- weight transpose + bf16 convert into d_ws ----------------
// W1t[256][512], W2t[128][256], W3t[16][128]  (all [n][k], k contiguous)
__global__ __launch_bounds__(256) void wconv_kernel(
    const float* __restrict__ W1, const float* __restrict__ W2, const float* __restrict__ W3,
    unsigned short* __restrict__ W1t, unsigned short* __restrict__ W2t, unsigned short* __restrict__ W3t){
  int t = blockIdx.x * 256 + threadIdx.x;
  if (t < 256*512){
    int n = t >> 9, k = t & 511;
    W1t[t] = f2bf(W1[k*256 + n]);
  } else if (t < 256*512 + 128*256){
    int i = t - 256*512; int n = i >> 8, k = i & 255;
    W2t[i] = f2bf(W2[k*128 + n]);
  } else if (t < 256*512 + 128*256 + 16*128){
    int i = t - (256*512 + 128*256); int n = i >> 7, k = i & 127;
    W3t[i] = f2bf(W3[k*16 + n]);
  }
}

// ---------------- subject LayerNorm: one wave per row, pure f32 ----------------
__global__ __launch_bounds__(256) void ln_kernel(
    const float* __restrict__ x, const int* __restrict__ groups,
    const float* __restrict__ gammas, const float* __restrict__ betas,
    float* __restrict__ out){
  int row  = blockIdx.x * 4 + (threadIdx.x >> 6);
  int lane = threadIdx.x & 63;
  const float4* xr = (const float4*)(x + (size_t)row * 512);
  float4 a = xr[lane];
  float4 b = xr[lane + 64];
  float s = a.x + a.y + a.z + a.w + b.x + b.y + b.z + b.w;
  float q = a.x*a.x + a.y*a.y + a.z*a.z + a.w*a.w
          + b.x*b.x + b.y*b.y + b.z*b.z + b.w*b.w;
  #pragma unroll
  for (int o = 32; o > 0; o >>= 1){
    s += __shfl_xor(s, o);
    q += __shfl_xor(q, o);
  }
  float mu  = s * (1.0f/512.0f);
  float var = q * (1.0f/512.0f) - mu*mu;
  float rs  = rsqrtf(var + 1e-5f);
  int gi  = groups[row];
  int idx = ((unsigned)gi < (unsigned)NSUB) ? gi : NSUB;
  const float4* gr = (const float4*)(gammas + (size_t)idx * 512);
  const float4* br = (const float4*)(betas  + (size_t)idx * 512);
  float4 g0 = gr[lane], g1 = gr[lane + 64];
  float4 e0 = br[lane], e1 = br[lane + 64];
  float4 o0, o1;
  o0.x = (a.x - mu) * rs * g0.x + e0.x;
  o0.y = (a.y - mu) * rs * g0.y + e0.y;
  o0.z = (a.z - mu) * rs * g0.z + e0.z;
  o0.w = (a.w - mu) * rs * g0.w + e0.w;
  o1.x = (b.x - mu) * rs * g1.x + e1.x;
  o1.y = (b.y - mu) * rs * g1.y + e1.y;
  o1.z = (b.z - mu) * rs * g1.z + e1.z;
  o1.w = (b.w - mu) * rs * g1.w + e1.w;
  float4* orow = (float4*)(out + (size_t)row * 512);
  orow[lane]      = o0;
  orow[lane + 64] = o1;
}

// ---------------- fused 3-GEMM MLP with bf16 MFMA ----------------
// block = 256 threads (4 waves), 64 rows per block.
// LDS: Xs [64][64] bf16 swz (8KB) | Ws pad-80B (20KB) | h1s [64][256] bf16 swz (32KB)
// h2s [64][128] overlays h1s after GEMM2 (h1 dead by then).
__global__ __launch_bounds__(256, 2) void mlp_kernel(
    const float* __restrict__ x,
    const unsigned short* __restrict__ W1t, const float* __restrict__ b1,
    const unsigned short* __restrict__ W2t, const float* __restrict__ b2,
    const unsigned short* __restrict__ W3t, const float* __restrict__ b3,
    float* __restrict__ out2){
  __shared__ __align__(16) uint8_t smem[61440];
  constexpr int OFF_XS = 0;
  constexpr int OFF_WS = 8192;
  constexpr int OFF_H1 = 28672;

  const int tid  = threadIdx.x;
  const int wave = tid >> 6;
  const int lane = tid & 63;
  const int l15  = lane & 15;
  const int g4   = lane >> 4;      // 0..3
  const int row0 = blockIdx.x * 64;

  // ======== GEMM1: 64x256 = x(64x512) @ W1, K-chunks of 64 ========
  f32x4 acc1[4][4] = {};
  for (int kc = 0; kc < 8; ++kc){
    __syncthreads();   // previous chunk's MFMAs done before Xs overwrite
    #pragma unroll
    for (int i = 0; i < 2; ++i){
      int idx = tid + i*256;          // 0..511
      int r   = idx >> 3;             // row 0..63
      int c8  = idx & 7;              // 16B chunk within 64-elem row
      const float* gp = x + (size_t)(row0 + r)*512 + kc*64 + c8*8;
      float4 f0 = *(const float4*)gp;
      float4 f1 = *(const float4*)(gp + 4);
      uint32_t p0 = (uint32_t)f2bf(f0.x) | ((uint32_t)f2bf(f0.y) << 16);
      uint32_t p1 = (uint32_t)f2bf(f0.z) | ((uint32_t)f2bf(f0.w) << 16);
      uint32_t p2 = (uint32_t)f2bf(f1.x) | ((uint32_t)f2bf(f1.y) << 16);
      uint32_t p3 = (uint32_t)f2bf(f1.z) | ((uint32_t)f2bf(f1.w) << 16);
      u32x4 pv; pv.x = p0; pv.y = p1; pv.z = p2; pv.w = p3;
      int byte = r*128 + ((c8*16) ^ ((r & 7) << 4));
      *(u32x4*)(smem + OFF_XS + byte) = pv;
    }
    #pragma unroll
    for (int ks = 0; ks < 2; ++ks){
      __syncthreads();   // prior MFMAs done before Ws overwrite (also covers Xs ready)
      int kg = kc*64 + ks*32;
      #pragma unroll
      for (int i = 0; i < 4; ++i){
        int idx = tid + i*256;        // 0..1023
        int n = idx >> 2, c = idx & 3;
        u32x4 v = *(const u32x4*)(W1t + (size_t)n*512 + kg + c*8);
        *(u32x4*)(smem + OFF_WS + n*80 + c*16) = v;
      }
      __syncthreads();
      bf16x8 af[4], bfr[4];
      #pragma unroll
      for (int m = 0; m < 4; ++m){
        int r = m*16 + l15;
        int byte = r*128 + (((ks*64) + g4*16) ^ ((r & 7) << 4));
        af[m] = *(const bf16x8*)(smem + OFF_XS + byte);
      }
      #pragma unroll
      for (int n = 0; n < 4; ++n){
        int nn = wave*64 + n*16 + l15;
        bfr[n] = *(const bf16x8*)(smem + OFF_WS + nn*80 + g4*16);
      }
      #pragma unroll
      for (int m = 0; m < 4; ++m)
        #pragma unroll
        for (int n = 0; n < 4; ++n)
          acc1[m][n] = __builtin_amdgcn_mfma_f32_16x16x32_bf16(af[m], bfr[n], acc1[m][n], 0, 0, 0);
    }
  }
  // epilogue 1: bias + exact GELU -> h1s (bf16, swizzled). GEMM2's first sync
  // orders these writes before any h1s read.
  #pragma unroll
  for (int n = 0; n < 4; ++n){
    int col = wave*64 + n*16 + l15;
    float bias = b1[col];
    #pragma unroll
    for (int m = 0; m < 4; ++m){
      #pragma unroll
      for (int r = 0; r < 4; ++r){
        int row = m*16 + g4*4 + r;
        float v = gelu_exact(acc1[m][n][r] + bias);
        *(unsigned short*)(smem + OFF_H1 + row*512 + ((col*2) ^ ((row & 7) << 4))) = f2bf(v);
      }
    }
  }

  // ======== GEMM2: 64x128 = h1(64x256) @ W2 ========
  f32x4 acc2[4][2] = {};
  for (int ks = 0; ks < 8; ++ks){
    __syncthreads();
    #pragma unroll
    for (int i = 0; i < 2; ++i){
      int idx = tid + i*256;          // 0..511
      int n = idx >> 2, c = idx & 3;  // n 0..127
      u32x4 v = *(const u32x4*)(W2t + (size_t)n*256 + ks*32 + c*8);
      *(u32x4*)(smem + OFF_WS + n*80 + c*16) = v;
    }
    __syncthreads();
    bf16x8 af[4], bfr[2];
    #pragma unroll
    for (int m = 0; m < 4; ++m){
      int r = m*16 + l15;
      int byte = r*512 + ((ks*64 + g4*16) ^ ((r & 7) << 4));
      af[m] = *(const bf16x8*)(smem + OFF_H1 + byte);
    }
    #pragma unroll
    for (int n = 0; n < 2; ++n){
      int nn = wave*32 + n*16 + l15;
      bfr[n] = *(const bf16x8*)(smem + OFF_WS + nn*80 + g4*16);
    }
    #pragma unroll
    for (int m = 0; m < 4; ++m)
      #pragma unroll
      for (int n = 0; n < 2; ++n)
        acc2[m][n] = __builtin_amdgcn_mfma_f32_16x16x32_bf16(af[m], bfr[n], acc2[m][n], 0, 0, 0);
  }
  __syncthreads();   // all h1s reads done: h2s may overlay OFF_H1
  #pragma unroll
  for (int n = 0; n < 2; ++n){
    int col = wave*32 + n*16 + l15;
    float bias = b2[col];
    #pragma unroll
    for (int m = 0; m < 4; ++m){
      #pragma unroll
      for (int r = 0; r < 4; ++r){
        int row = m*16 + g4*4 + r;
        float v = gelu_exact(acc2[m][n][r] + bias);
        *(unsigned short*)(smem + OFF_H1 + row*256 + ((col*2) ^ ((row & 7) << 4))) = f2bf(v);
      }
    }
  }
  // stage W3t [16][128] into Ws region (272B padded rows); no Ws readers remain
  {
    int n = tid >> 4, c = tid & 15;
    u32x4 v = *(const u32x4*)(W3t + n*128 + c*8);
    *(u32x4*)(smem + OFF_WS + n*272 + c*16) = v;
  }
  __syncthreads();   // h2s + W3s ready

  // ======== GEMM3: 64x16 = h2(64x128) @ W3; wave w owns rows 16w..16w+15 ========
  f32x4 acc3 = {};
  #pragma unroll
  for (int ks = 0; ks < 4; ++ks){
    int r = wave*16 + l15;
    int byte = r*256 + ((ks*64 + g4*16) ^ ((r & 7) << 4));
    bf16x8 a = *(const bf16x8*)(smem + OFF_H1 + byte);
    bf16x8 b = *(const bf16x8*)(smem + OFF_WS + l15*272 + ks*64 + g4*16);
    acc3 = __builtin_amdgcn_mfma_f32_16x16x32_bf16(a, b, acc3, 0, 0, 0);
  }
  {
    float bias = b3[l15];
    #pragma unroll
    for (int r = 0; r < 4; ++r){
      int grow = row0 + wave*16 + g4*4 + r;
      out2[(size_t)grow*16 + l15] = acc3[r] + bias;
    }
  }
}

// ---------------- correctness-only fallback if d_ws is too small ----------------
__global__ __launch_bounds__(256) void mlp_naive(
    const float* __restrict__ x,
    const float* __restrict__ W1, const float* __restrict__ b1,
    const float* __restrict__ W2, const float* __restrict__ b2,
    const float* __restrict__ W3, const float* __restrict__ b3,
    float* __restrict__ out2){
  __shared__ float xr[512];
  __shared__ float h1[256];
  __shared__ float h2[128];
  int row = blockIdx.x, t = threadIdx.x;
  xr[t]       = x[(size_t)row*512 + t];
  xr[t + 256] = x[(size_t)row*512 + t + 256];
  __syncthreads();
  {
    float s = 0.f;
    for (int k = 0; k < 512; ++k) s += xr[k] * W1[k*256 + t];
    h1[t] = gelu_exact(s + b1[t]);
  }
  __syncthreads();
  if (t < 128){
    float s = 0.f;
    for (int k = 0; k < 256; ++k) s += h1[k] * W2[k*128 + t];
    h2[t] = gelu_exact(s + b2[t]);
  }
  __syncthreads();
  if (t < 16){
    float s = 0.f;
    for (int k = 0; k < 128; ++k) s += h2[k] * W3[k*16 + t];
    out2[(size_t)row*16 + t] = s + b3[t];
  }
}

extern "C" void kernel_launch(void* const* d_in, const int* in_sizes, int n_in,
                              void* d_out, int out_size, void* d_ws, size_t ws_size,
                              hipStream_t stream){
  const float* x      = (const float*)d_in[0];
  const int*   groups = (const int*)d_in[1];
  const float* gammas = (const float*)d_in[2];
  const float* betas  = (const float*)d_in[3];
  const float* W1 = (const float*)d_in[4];
  const float* b1 = (const float*)d_in[5];
  const float* W2 = (const float*)d_in[6];
  const float* b2 = (const float*)d_in[7];
  const float* W3 = (const float*)d_in[8];
  const float* b3 = (const float*)d_in[9];
  float* out  = (float*)d_out;
  const int B = in_sizes[0] / 512;
  float* out2 = out + (size_t)B * 512;

  const size_t ws_need = (size_t)(256*512 + 128*256 + 16*128) * sizeof(unsigned short);
  if (ws_size >= ws_need){
    unsigned short* W1t = (unsigned short*)d_ws;
    unsigned short* W2t = W1t + 256*512;
    unsigned short* W3t = W2t + 128*256;
    int nconv = 256*512 + 128*256 + 16*128;
    wconv_kernel<<<(nconv + 255)/256, 256, 0, stream>>>(W1, W2, W3, W1t, W2t, W3t);
    mlp_kernel<<<B/64, 256, 0, stream>>>(x, W1t, b1, W2t, b2, W3t, b3, out2);
  } else {
    mlp_naive<<<B, 256, 0, stream>>>(x, W1, b1, W2, b2, W3, b3, out2);
  }
  ln_kernel<<<B/4, 256, 0, stream>>>(x, groups, gammas, betas, out);
}

// Round 2
// 231.473 us; speedup vs baseline: 1.0778x; 1.0778x over previous
//
#include <hip/hip_runtime.h>
#include <hip/hip_bf16.h>
#include <stdint.h>

#define NSUB 16

typedef short  bf16x8 __attribute__((ext_vector_type(8)));
typedef float  f32x4  __attribute__((ext_vector_type(4)));
typedef unsigned int u32x4 __attribute__((ext_vector_type(4)));

__device__ __forceinline__ float gelu_exact(float x){
  return 0.5f * x * (1.0f + erff(x * 0.70710678118654752440f));
}

__device__ __forceinline__ unsigned short f2bf(float f){
  union { float f; uint32_t u; } v; v.f = f;
  uint32_t u = v.u;
  return (unsigned short)((u + 0x7FFFu + ((u >> 16) & 1u)) >> 16);
}

__device__ __forceinline__ unsigned int pk2(float lo, float hi){
  union { __hip_bfloat162 b; unsigned int u; } c;
  c.b = __float22bfloat162_rn(make_float2(lo, hi));
  return c.u;
}

__device__ __forceinline__ bf16x8 as_bf(u32x4 v){
  union { u32x4 u; bf16x8 b; } c; c.u = v; return c.b;
}

// ---------------- weights -> bf16, MFMA-B-fragment order, into d_ws ----------
// Fragment layout: for (n,k): lane = ((k>>3)&3)*16 + (n&15), j = k&7,
// flat = ((ks*NT + nn)*64 + lane)*8 + j  with ks = k>>5, nn = n>>4.
// A wave then loads one whole B-fragment as lane-indexed global_load_dwordx4.
__global__ __launch_bounds__(256) void wconv_kernel(
    const float* __restrict__ W1, const float* __restrict__ W2, const float* __restrict__ W3,
    unsigned short* __restrict__ W1f, unsigned short* __restrict__ W2f, unsigned short* __restrict__ W3f){
  int t = blockIdx.x * 256 + threadIdx.x;
  if (t < 131072){                       // W1: K=512 (ks 0..15), N=256 (nn 0..15)
    int n = t >> 9, k = t & 511;
    int lane = ((k >> 3) & 3) * 16 + (n & 15);
    int idx = (((k >> 5) * 16 + (n >> 4)) * 64 + lane) * 8 + (k & 7);
    W1f[idx] = f2bf(W1[k*256 + n]);
  } else if (t < 131072 + 32768){        // W2: K=256 (ks 0..7), N=128 (nn 0..7)
    int i = t - 131072; int n = i >> 8, k = i & 255;
    int lane = ((k >> 3) & 3) * 16 + (n & 15);
    int idx = (((k >> 5) * 8 + (n >> 4)) * 64 + lane) * 8 + (k & 7);
    W2f[idx] = f2bf(W2[k*128 + n]);
  } else if (t < 131072 + 32768 + 2048){ // W3: K=128 (ks 0..3), N=16 (nn=0)
    int i = t - (131072 + 32768); int n = i >> 7, k = i & 127;
    int lane = ((k >> 3) & 3) * 16 + n;
    int idx = ((k >> 5) * 64 + lane) * 8 + (k & 7);
    W3f[idx] = f2bf(W3[k*16 + n]);
  }
}

// ---------------- subject LayerNorm: one wave per row, pure f32 ----------------
__global__ __launch_bounds__(256) void ln_kernel(
    const float* __restrict__ x, const int* __restrict__ groups,
    const float* __restrict__ gammas, const float* __restrict__ betas,
    float* __restrict__ out){
  int row  = blockIdx.x * 4 + (threadIdx.x >> 6);
  int lane = threadIdx.x & 63;
  const float4* xr = (const float4*)(x + (size_t)row * 512);
  float4 a = xr[lane];
  float4 b = xr[lane + 64];
  float s = a.x + a.y + a.z + a.w + b.x + b.y + b.z + b.w;
  float q = a.x*a.x + a.y*a.y + a.z*a.z + a.w*a.w
          + b.x*b.x + b.y*b.y + b.z*b.z + b.w*b.w;
  #pragma unroll
  for (int o = 32; o > 0; o >>= 1){
    s += __shfl_xor(s, o);
    q += __shfl_xor(q, o);
  }
  float mu  = s * (1.0f/512.0f);
  float var = q * (1.0f/512.0f) - mu*mu;
  float rs  = rsqrtf(var + 1e-5f);
  int gi  = groups[row];
  int idx = ((unsigned)gi < (unsigned)NSUB) ? gi : NSUB;
  const float4* gr = (const float4*)(gammas + (size_t)idx * 512);
  const float4* br = (const float4*)(betas  + (size_t)idx * 512);
  float4 g0 = gr[lane], g1 = gr[lane + 64];
  float4 e0 = br[lane], e1 = br[lane + 64];
  float4 o0, o1;
  o0.x = (a.x - mu) * rs * g0.x + e0.x;
  o0.y = (a.y - mu) * rs * g0.y + e0.y;
  o0.z = (a.z - mu) * rs * g0.z + e0.z;
  o0.w = (a.w - mu) * rs * g0.w + e0.w;
  o1.x = (b.x - mu) * rs * g1.x + e1.x;
  o1.y = (b.y - mu) * rs * g1.y + e1.y;
  o1.z = (b.z - mu) * rs * g1.z + e1.z;
  o1.w = (b.w - mu) * rs * g1.w + e1.w;
  float4* orow = (float4*)(out + (size_t)row * 512);
  orow[lane]      = o0;
  orow[lane + 64] = o1;
}

// ---------------- fused 3-GEMM MLP ----------------
// 256 thr / 4 waves, BM=64, grid 2048.
// W fragments: direct global->reg, double-buffered (no LDS, no W barriers).
// X: LDS dbuf 2x8KB, XOR-swizzled, 1 barrier per 64-K chunk, 2-chunk reg prefetch.
// h1 (32KB) / h2 (16KB) in LDS, swizzled; one barrier each before their readers.
__global__ __launch_bounds__(256) void mlp_kernel(
    const float* __restrict__ x,
    const unsigned short* __restrict__ W1f, const float* __restrict__ b1,
    const unsigned short* __restrict__ W2f, const float* __restrict__ b2,
    const unsigned short* __restrict__ W3f, const float* __restrict__ b3,
    float* __restrict__ out2){
  __shared__ __align__(16) uint8_t smem[65536];
  constexpr int OFF_XS = 0;       // 2 x 8KB double buffer
  constexpr int OFF_H1 = 16384;   // 32KB
  constexpr int OFF_H2 = 49152;   // 16KB

  const int tid  = threadIdx.x;
  const int wave = tid >> 6;
  const int lane = tid & 63;
  const int l15  = lane & 15;
  const int g4   = lane >> 4;
  const int row0 = blockIdx.x * 64;

  // bias preload (L2)
  float b1v[4], b2v[2], b3v;
  #pragma unroll
  for (int n = 0; n < 4; ++n) b1v[n] = b1[wave*64 + n*16 + l15];
  #pragma unroll
  for (int n = 0; n < 2; ++n) b2v[n] = b2[wave*32 + n*16 + l15];
  b3v = b3[l15];

  // X staging map: thread -> (row sr, 16-float col group sc) of the 64x64 chunk
  const int sr  = tid >> 2;
  const int sc  = tid & 3;
  const float* xg = x + (size_t)(row0 + sr)*512 + sc*16;
  const int swz = (sr & 7) << 4;
  const int wb0 = sr*128 + ((sc*32     ) ^ swz);
  const int wb1 = sr*128 + ((sc*32 + 16) ^ swz);

  f32x4 xraw[2][4];
  u32x4 braw[2][4];

  // prologue: chunks 0,1 of x; ks=0 B-fragments
  #pragma unroll
  for (int i = 0; i < 4; ++i) xraw[0][i] = *(const f32x4*)(xg + 0*64 + i*4);
  #pragma unroll
  for (int i = 0; i < 4; ++i) xraw[1][i] = *(const f32x4*)(xg + 1*64 + i*4);
  #pragma unroll
  for (int n = 0; n < 4; ++n)
    braw[0][n] = *(const u32x4*)(W1f + (size_t)(((0*16 + wave*4 + n)*64 + lane)*8));

  // ======== GEMM1: 64x256 = x(64x512) @ W1 ========
  f32x4 acc1[4][4] = {};
  #pragma unroll
  for (int t = 0; t < 8; ++t){
    const int cb = t & 1;
    // convert + store chunk t into Xs buf cb
    {
      unsigned int w0 = pk2(xraw[cb][0].x, xraw[cb][0].y);
      unsigned int w1 = pk2(xraw[cb][0].z, xraw[cb][0].w);
      unsigned int w2 = pk2(xraw[cb][1].x, xraw[cb][1].y);
      unsigned int w3 = pk2(xraw[cb][1].z, xraw[cb][1].w);
      unsigned int w4 = pk2(xraw[cb][2].x, xraw[cb][2].y);
      unsigned int w5 = pk2(xraw[cb][2].z, xraw[cb][2].w);
      unsigned int w6 = pk2(xraw[cb][3].x, xraw[cb][3].y);
      unsigned int w7 = pk2(xraw[cb][3].z, xraw[cb][3].w);
      u32x4 lo; lo.x = w0; lo.y = w1; lo.z = w2; lo.w = w3;
      u32x4 hi; hi.x = w4; hi.y = w5; hi.z = w6; hi.w = w7;
      *(u32x4*)(smem + OFF_XS + cb*8192 + wb0) = lo;
      *(u32x4*)(smem + OFF_XS + cb*8192 + wb1) = hi;
    }
    __syncthreads();
    // prefetch chunk t+2 into the regs just freed
    if (t < 6){
      #pragma unroll
      for (int i = 0; i < 4; ++i)
        xraw[cb][i] = *(const f32x4*)(xg + (t+2)*64 + i*4);
    }
    // compute the 2 K=32 steps of this chunk
    #pragma unroll
    for (int ks = 0; ks < 2; ++ks){
      const int g = t*2 + ks;
      if (g < 15){
        #pragma unroll
        for (int n = 0; n < 4; ++n)
          braw[(g+1)&1][n] = *(const u32x4*)(W1f + (size_t)((((g+1)*16 + wave*4 + n)*64 + lane)*8));
      }
      bf16x8 a[4];
      #pragma unroll
      for (int m = 0; m < 4; ++m){
        int row = m*16 + l15;
        a[m] = *(const bf16x8*)(smem + OFF_XS + cb*8192 + row*128 + ((ks*64 + g4*16) ^ ((row & 7) << 4)));
      }
      #pragma unroll
      for (int m = 0; m < 4; ++m)
        #pragma unroll
        for (int n = 0; n < 4; ++n)
          acc1[m][n] = __builtin_amdgcn_mfma_f32_16x16x32_bf16(a[m], as_bf(braw[g & 1][n]), acc1[m][n], 0, 0, 0);
    }
  }

  // GEMM2 B prologue (issue before epilogue VALU to hide L2 latency)
  u32x4 b2raw[2][2];
  #pragma unroll
  for (int n = 0; n < 2; ++n)
    b2raw[0][n] = *(const u32x4*)(W2f + (size_t)(((0*8 + wave*2 + n)*64 + lane)*8));

  // epilogue 1: bias + exact GELU -> h1 (bf16, swizzled)
  #pragma unroll
  for (int n = 0; n < 4; ++n){
    #pragma unroll
    for (int m = 0; m < 4; ++m){
      #pragma unroll
      for (int r = 0; r < 4; ++r){
        int row = m*16 + g4*4 + r;
        int col = wave*64 + n*16 + l15;
        float v = gelu_exact(acc1[m][n][r] + b1v[n]);
        *(unsigned short*)(smem + OFF_H1 + row*512 + ((col*2) ^ ((row & 7) << 4))) = f2bf(v);
      }
    }
  }
  __syncthreads();

  // ======== GEMM2: 64x128 = h1(64x256) @ W2 ========
  f32x4 acc2[4][2] = {};
  #pragma unroll
  for (int g = 0; g < 8; ++g){
    if (g < 7){
      #pragma unroll
      for (int n = 0; n < 2; ++n)
        b2raw[(g+1)&1][n] = *(const u32x4*)(W2f + (size_t)((((g+1)*8 + wave*2 + n)*64 + lane)*8));
    }
    bf16x8 a[4];
    #pragma unroll
    for (int m = 0; m < 4; ++m){
      int row = m*16 + l15;
      a[m] = *(const bf16x8*)(smem + OFF_H1 + row*512 + ((g*64 + g4*16) ^ ((row & 7) << 4)));
    }
    #pragma unroll
    for (int m = 0; m < 4; ++m)
      #pragma unroll
      for (int n = 0; n < 2; ++n)
        acc2[m][n] = __builtin_amdgcn_mfma_f32_16x16x32_bf16(a[m], as_bf(b2raw[g & 1][n]), acc2[m][n], 0, 0, 0);
  }

  // W3 fragment prefetch
  u32x4 b3raw[4];
  #pragma unroll
  for (int ks = 0; ks < 4; ++ks)
    b3raw[ks] = *(const u32x4*)(W3f + (size_t)((ks*64 + lane)*8));

  // epilogue 2: bias + GELU -> h2 (bf16, swizzled)
  #pragma unroll
  for (int n = 0; n < 2; ++n){
    #pragma unroll
    for (int m = 0; m < 4; ++m){
      #pragma unroll
      for (int r = 0; r < 4; ++r){
        int row = m*16 + g4*4 + r;
        int col = wave*32 + n*16 + l15;
        float v = gelu_exact(acc2[m][n][r] + b2v[n]);
        *(unsigned short*)(smem + OFF_H2 + row*256 + ((col*2) ^ ((row & 7) << 4))) = f2bf(v);
      }
    }
  }
  __syncthreads();

  // ======== GEMM3: 64x16 = h2(64x128) @ W3; wave w owns rows 16w..16w+15 ========
  f32x4 acc3 = {};
  #pragma unroll
  for (int ks = 0; ks < 4; ++ks){
    int row = wave*16 + l15;
    bf16x8 a = *(const bf16x8*)(smem + OFF_H2 + row*256 + ((ks*64 + g4*16) ^ ((row & 7) << 4)));
    acc3 = __builtin_amdgcn_mfma_f32_16x16x32_bf16(a, as_bf(b3raw[ks]), acc3, 0, 0, 0);
  }
  {
    #pragma unroll
    for (int r = 0; r < 4; ++r){
      int grow = row0 + wave*16 + g4*4 + r;
      out2[(size_t)grow*16 + l15] = acc3[r] + b3v;
    }
  }
}

// ---------------- correctness-only fallback if d_ws is too small ----------------
__global__ __launch_bounds__(256) void mlp_naive(
    const float* __restrict__ x,
    const float* __restrict__ W1, const float* __restrict__ b1,
    const float* __restrict__ W2, const float* __restrict__ b2,
    const float* __restrict__ W3, const float* __restrict__ b3,
    float* __restrict__ out2){
  __shared__ float xr[512];
  __shared__ float h1[256];
  __shared__ float h2[128];
  int row = blockIdx.x, t = threadIdx.x;
  xr[t]       = x[(size_t)row*512 + t];
  xr[t + 256] = x[(size_t)row*512 + t + 256];
  __syncthreads();
  {
    float s = 0.f;
    for (int k = 0; k < 512; ++k) s += xr[k] * W1[k*256 + t];
    h1[t] = gelu_exact(s + b1[t]);
  }
  __syncthreads();
  if (t < 128){
    float s = 0.f;
    for (int k = 0; k < 256; ++k) s += h1[k] * W2[k*128 + t];
    h2[t] = gelu_exact(s + b2[t]);
  }
  __syncthreads();
  if (t < 16){
    float s = 0.f;
    for (int k = 0; k < 128; ++k) s += h2[k] * W3[k*16 + t];
    out2[(size_t)row*16 + t] = s + b3[t];
  }
}

extern "C" void kernel_launch(void* const* d_in, const int* in_sizes, int n_in,
                              void* d_out, int out_size, void* d_ws, size_t ws_size,
                              hipStream_t stream){
  const float* x      = (const float*)d_in[0];
  const int*   groups = (const int*)d_in[1];
  const float* gammas = (const float*)d_in[2];
  const float* betas  = (const float*)d_in[3];
  const float* W1 = (const float*)d_in[4];
  const float* b1 = (const float*)d_in[5];
  const float* W2 = (const float*)d_in[6];
  const float* b2 = (const float*)d_in[7];
  const float* W3 = (const float*)d_in[8];
  const float* b3 = (const float*)d_in[9];
  float* out  = (float*)d_out;
  const int B = in_sizes[0] / 512;
  float* out2 = out + (size_t)B * 512;

  const size_t ws_need = (size_t)(131072 + 32768 + 2048) * sizeof(unsigned short);
  if (ws_size >= ws_need){
    unsigned short* W1f = (unsigned short*)d_ws;
    unsigned short* W2f = W1f + 131072;
    unsigned short* W3f = W2f + 32768;
    int nconv = 131072 + 32768 + 2048;
    wconv_kernel<<<(nconv + 255)/256, 256, 0, stream>>>(W1, W2, W3, W1f, W2f, W3f);
    mlp_kernel<<<B/64, 256, 0, stream>>>(x, W1f, b1, W2f, b2, W3f, b3, out2);
  } else {
    mlp_naive<<<B, 256, 0, stream>>>(x, W1, b1, W2, b2, W3, b3, out2);
  }
  ln_kernel<<<B/4, 256, 0, stream>>>(x, groups, gammas, betas, out);
}

// Round 3
// 231.057 us; speedup vs baseline: 1.0798x; 1.0018x over previous
//
#include <hip/hip_runtime.h>
#include <hip/hip_bf16.h>
#include <stdint.h>

#define NSUB 16

typedef short  bf16x8 __attribute__((ext_vector_type(8)));
typedef float  f32x4  __attribute__((ext_vector_type(4)));
typedef unsigned int u32x4 __attribute__((ext_vector_type(4)));

__device__ __forceinline__ float gelu_exact(float x){
  return 0.5f * x * (1.0f + erff(x * 0.70710678118654752440f));
}

__device__ __forceinline__ unsigned short f2bf(float f){
  union { float f; uint32_t u; } v; v.f = f;
  uint32_t u = v.u;
  return (unsigned short)((u + 0x7FFFu + ((u >> 16) & 1u)) >> 16);
}

__device__ __forceinline__ unsigned int pk2(float lo, float hi){
  union { __hip_bfloat162 b; unsigned int u; } c;
  c.b = __float22bfloat162_rn(make_float2(lo, hi));
  return c.u;
}

__device__ __forceinline__ bf16x8 as_bf(u32x4 v){
  union { u32x4 u; bf16x8 b; } c; c.u = v; return c.b;
}

__device__ __forceinline__ float bflo(unsigned int u){
  union { unsigned int u; float f; } c; c.u = u << 16; return c.f;
}
__device__ __forceinline__ float bfhi(unsigned int u){
  union { unsigned int u; float f; } c; c.u = u & 0xffff0000u; return c.f;
}

// ---------------- weights -> bf16, MFMA-B-fragment order, into d_ws ----------
// flat = ((ks*NT + nn)*64 + lane)*8 + j ; lane = ((k>>3)&3)*16 + (n&15), j = k&7
__global__ __launch_bounds__(256) void wconv_kernel(
    const float* __restrict__ W1, const float* __restrict__ W2, const float* __restrict__ W3,
    unsigned short* __restrict__ W1f, unsigned short* __restrict__ W2f, unsigned short* __restrict__ W3f){
  int t = blockIdx.x * 256 + threadIdx.x;
  if (t < 131072){                       // W1: K=512, N=256
    int n = t >> 9, k = t & 511;
    int lane = ((k >> 3) & 3) * 16 + (n & 15);
    int idx = (((k >> 5) * 16 + (n >> 4)) * 64 + lane) * 8 + (k & 7);
    W1f[idx] = f2bf(W1[k*256 + n]);
  } else if (t < 131072 + 32768){        // W2: K=256, N=128
    int i = t - 131072; int n = i >> 8, k = i & 255;
    int lane = ((k >> 3) & 3) * 16 + (n & 15);
    int idx = (((k >> 5) * 8 + (n >> 4)) * 64 + lane) * 8 + (k & 7);
    W2f[idx] = f2bf(W2[k*128 + n]);
  } else if (t < 131072 + 32768 + 2048){ // W3: K=128, N=16
    int i = t - (131072 + 32768); int n = i >> 7, k = i & 127;
    int lane = ((k >> 3) & 3) * 16 + n;
    int idx = ((k >> 5) * 64 + lane) * 8 + (k & 7);
    W3f[idx] = f2bf(W3[k*16 + n]);
  }
}

// ---------------- fused LN + 3-GEMM MLP ----------------
// 256 thr / 4 waves, 64 rows/block, grid 2048.
// LDS 64KB: X [64][512]bf16 swizzled; H1 (32KB) overlays X[0:32K] after GEMM1;
// H2 (16KB) overlays X[32K:48K] after GEMM2. 4 barriers total.
__global__ __launch_bounds__(256) void fused_kernel(
    const float* __restrict__ x, const int* __restrict__ groups,
    const float* __restrict__ gammas, const float* __restrict__ betas,
    const unsigned short* __restrict__ W1f, const float* __restrict__ b1,
    const unsigned short* __restrict__ W2f, const float* __restrict__ b2,
    const unsigned short* __restrict__ W3f, const float* __restrict__ b3,
    float* __restrict__ ln_out, float* __restrict__ out2){
  __shared__ __align__(16) uint8_t smem[65536];
  constexpr int OFF_H2 = 32768;

  const int tid  = threadIdx.x;
  const int wave = tid >> 6;
  const int lane = tid & 63;
  const int l15  = lane & 15;
  const int g4   = lane >> 4;
  const int row0 = blockIdx.x * 64;

  // ---- phase 0: stage x -> LDS bf16 (swizzled) + f32 row stats ----
  const int sr  = tid >> 2;           // row 0..63
  const int sc  = tid & 3;            // 16-float column group
  const int swz = (sr & 7) << 4;
  const int w0  = (sc*32)      ^ swz;
  const int w1  = (sc*32 + 16) ^ swz;
  uint8_t* xrow = smem + sr*1024;
  const float* xg = x + (size_t)(row0 + sr)*512 + sc*16;

  float s = 0.f, q = 0.f;
  #pragma unroll
  for (int t = 0; t < 8; ++t){
    f32x4 v[4];
    #pragma unroll
    for (int i = 0; i < 4; ++i) v[i] = *(const f32x4*)(xg + t*64 + i*4);
    #pragma unroll
    for (int i = 0; i < 4; ++i){
      s += v[i].x + v[i].y + v[i].z + v[i].w;
      q += v[i].x*v[i].x + v[i].y*v[i].y + v[i].z*v[i].z + v[i].w*v[i].w;
    }
    u32x4 lo, hi;
    lo.x = pk2(v[0].x, v[0].y); lo.y = pk2(v[0].z, v[0].w);
    lo.z = pk2(v[1].x, v[1].y); lo.w = pk2(v[1].z, v[1].w);
    hi.x = pk2(v[2].x, v[2].y); hi.y = pk2(v[2].z, v[2].w);
    hi.z = pk2(v[3].x, v[3].y); hi.w = pk2(v[3].z, v[3].w);
    *(u32x4*)(xrow + t*128 + w0) = lo;
    *(u32x4*)(xrow + t*128 + w1) = hi;
  }
  s += __shfl_xor(s, 1); s += __shfl_xor(s, 2);
  q += __shfl_xor(q, 1); q += __shfl_xor(q, 2);
  float mu  = s * (1.0f/512.0f);
  float var = q * (1.0f/512.0f) - mu*mu;
  float rs  = rsqrtf(var + 1e-5f);
  float nmr = -mu * rs;
  int gi   = groups[row0 + sr];
  int gidx = ((unsigned)gi < (unsigned)NSUB) ? gi : NSUB;

  // ---- phase 1: LN output (reads back own LDS bf16; stores drain under GEMM1) ----
  {
    const float* gpr = gammas + (size_t)gidx*512 + sc*16;
    const float* bpr = betas  + (size_t)gidx*512 + sc*16;
    float* op = ln_out + (size_t)(row0 + sr)*512 + sc*16;
    #pragma unroll
    for (int t = 0; t < 8; ++t){
      u32x4 lo = *(const u32x4*)(xrow + t*128 + w0);
      u32x4 hi = *(const u32x4*)(xrow + t*128 + w1);
      f32x4 g[4], b[4];
      #pragma unroll
      for (int i = 0; i < 4; ++i){
        g[i] = *(const f32x4*)(gpr + t*64 + i*4);
        b[i] = *(const f32x4*)(bpr + t*64 + i*4);
      }
      float xv[16];
      xv[0]=bflo(lo.x); xv[1]=bfhi(lo.x); xv[2]=bflo(lo.y); xv[3]=bfhi(lo.y);
      xv[4]=bflo(lo.z); xv[5]=bfhi(lo.z); xv[6]=bflo(lo.w); xv[7]=bfhi(lo.w);
      xv[8]=bflo(hi.x); xv[9]=bfhi(hi.x); xv[10]=bflo(hi.y); xv[11]=bfhi(hi.y);
      xv[12]=bflo(hi.z); xv[13]=bfhi(hi.z); xv[14]=bflo(hi.w); xv[15]=bfhi(hi.w);
      #pragma unroll
      for (int i = 0; i < 4; ++i){
        f32x4 o;
        o.x = fmaf(fmaf(xv[i*4+0], rs, nmr), g[i].x, b[i].x);
        o.y = fmaf(fmaf(xv[i*4+1], rs, nmr), g[i].y, b[i].y);
        o.z = fmaf(fmaf(xv[i*4+2], rs, nmr), g[i].z, b[i].z);
        o.w = fmaf(fmaf(xv[i*4+3], rs, nmr), g[i].w, b[i].w);
        *(f32x4*)(op + t*64 + i*4) = o;
      }
    }
  }

  // bias preload
  float b1v[4], b2v[2], b3v;
  #pragma unroll
  for (int n = 0; n < 4; ++n) b1v[n] = b1[wave*64 + n*16 + l15];
  #pragma unroll
  for (int n = 0; n < 2; ++n) b2v[n] = b2[wave*32 + n*16 + l15];
  b3v = b3[l15];

  __syncthreads();   // X fully staged (also orders LN LDS reads; drains LN stores)

  // ---- phase 2: GEMM1 64x256, K=512, zero barriers ----
  // two-pointer trick: A addr = pA[m][g&1] + (g>>1)*128 (swizzle folded into bases)
  int baseA[4][2];
  #pragma unroll
  for (int m = 0; m < 4; ++m){
    int row = m*16 + l15;
    int sw  = (row & 7) << 4;
    int bse = row*1024 + ((g4*16) ^ (sw & 0x30));
    int kx  = (row >> 2) & 1;
    baseA[m][0] = bse + ((0 ^ kx) << 6);
    baseA[m][1] = bse + ((1 ^ kx) << 6);
  }
  u32x4 braw[2][4];
  #pragma unroll
  for (int n = 0; n < 4; ++n)
    braw[0][n] = *(const u32x4*)(W1f + (size_t)(((wave*4 + n)*64 + lane)*8));
  f32x4 acc1[4][4] = {};
  #pragma unroll
  for (int g = 0; g < 16; ++g){
    if (g < 15){
      #pragma unroll
      for (int n = 0; n < 4; ++n)
        braw[(g+1)&1][n] = *(const u32x4*)(W1f + (size_t)((((g+1)*16 + wave*4 + n)*64 + lane)*8));
    }
    bf16x8 a[4];
    #pragma unroll
    for (int m = 0; m < 4; ++m)
      a[m] = *(const bf16x8*)(smem + baseA[m][g & 1] + (g >> 1)*128);
    #pragma unroll
    for (int m = 0; m < 4; ++m)
      #pragma unroll
      for (int n = 0; n < 4; ++n)
        acc1[m][n] = __builtin_amdgcn_mfma_f32_16x16x32_bf16(a[m], as_bf(braw[g & 1][n]), acc1[m][n], 0, 0, 0);
  }
  __syncthreads();   // all X reads done; H1 may overlay X[0:32K]

  // GEMM2 B prologue (hide L2 latency under epilogue VALU)
  u32x4 b2raw[2][2];
  #pragma unroll
  for (int n = 0; n < 2; ++n)
    b2raw[0][n] = *(const u32x4*)(W2f + (size_t)(((wave*2 + n)*64 + lane)*8));

  // ---- epilogue 1: bias + GELU -> H1 bf16 swizzled at smem[0:32K] ----
  #pragma unroll
  for (int n = 0; n < 4; ++n){
    #pragma unroll
    for (int m = 0; m < 4; ++m){
      #pragma unroll
      for (int r = 0; r < 4; ++r){
        int row = m*16 + g4*4 + r;
        int col = wave*64 + n*16 + l15;
        float v = gelu_exact(acc1[m][n][r] + b1v[n]);
        *(unsigned short*)(smem + row*512 + ((col*2) ^ ((row & 7) << 4))) = f2bf(v);
      }
    }
  }
  __syncthreads();   // H1 ready

  // ---- phase 3: GEMM2 64x128, K=256 ----
  int baseH[4][2];
  #pragma unroll
  for (int m = 0; m < 4; ++m){
    int row = m*16 + l15;
    int sw  = (row & 7) << 4;
    int bse = row*512 + ((g4*16) ^ (sw & 0x30));
    int kx  = (row >> 2) & 1;
    baseH[m][0] = bse + ((0 ^ kx) << 6);
    baseH[m][1] = bse + ((1 ^ kx) << 6);
  }
  f32x4 acc2[4][2] = {};
  #pragma unroll
  for (int g = 0; g < 8; ++g){
    if (g < 7){
      #pragma unroll
      for (int n = 0; n < 2; ++n)
        b2raw[(g+1)&1][n] = *(const u32x4*)(W2f + (size_t)((((g+1)*8 + wave*2 + n)*64 + lane)*8));
    }
    bf16x8 a[4];
    #pragma unroll
    for (int m = 0; m < 4; ++m)
      a[m] = *(const bf16x8*)(smem + baseH[m][g & 1] + (g >> 1)*128);
    #pragma unroll
    for (int m = 0; m < 4; ++m)
      #pragma unroll
      for (int n = 0; n < 2; ++n)
        acc2[m][n] = __builtin_amdgcn_mfma_f32_16x16x32_bf16(a[m], as_bf(b2raw[g & 1][n]), acc2[m][n], 0, 0, 0);
  }

  // W3 fragment prefetch
  u32x4 b3raw[4];
  #pragma unroll
  for (int ks = 0; ks < 4; ++ks)
    b3raw[ks] = *(const u32x4*)(W3f + (size_t)((ks*64 + lane)*8));

  // ---- epilogue 2: bias + GELU -> H2 bf16 swizzled at smem[32K:48K] ----
  // (H2 disjoint from H1 -> no barrier needed before these writes)
  #pragma unroll
  for (int n = 0; n < 2; ++n){
    #pragma unroll
    for (int m = 0; m < 4; ++m){
      #pragma unroll
      for (int r = 0; r < 4; ++r){
        int row = m*16 + g4*4 + r;
        int col = wave*32 + n*16 + l15;
        float v = gelu_exact(acc2[m][n][r] + b2v[n]);
        *(unsigned short*)(smem + OFF_H2 + row*256 + ((col*2) ^ ((row & 7) << 4))) = f2bf(v);
      }
    }
  }
  __syncthreads();   // H2 ready

  // ---- phase 4: GEMM3 64x16, K=128; wave w owns rows 16w..16w+15 ----
  int baseG[2];
  {
    int row = wave*16 + l15;
    int sw  = (row & 7) << 4;
    int bse = OFF_H2 + row*256 + ((g4*16) ^ (sw & 0x30));
    int kx  = (row >> 2) & 1;
    baseG[0] = bse + ((0 ^ kx) << 6);
    baseG[1] = bse + ((1 ^ kx) << 6);
  }
  f32x4 acc3 = {};
  #pragma unroll
  for (int ks = 0; ks < 4; ++ks){
    bf16x8 a = *(const bf16x8*)(smem + baseG[ks & 1] + (ks >> 1)*128);
    acc3 = __builtin_amdgcn_mfma_f32_16x16x32_bf16(a, as_bf(b3raw[ks]), acc3, 0, 0, 0);
  }
  #pragma unroll
  for (int r = 0; r < 4; ++r){
    int grow = row0 + wave*16 + g4*4 + r;
    out2[(size_t)grow*16 + l15] = acc3[r] + b3v;
  }
}

// ---------------- fallback path (ws too small): naive MLP + standalone LN ----------------
__global__ __launch_bounds__(256) void ln_kernel(
    const float* __restrict__ x, const int* __restrict__ groups,
    const float* __restrict__ gammas, const float* __restrict__ betas,
    float* __restrict__ out){
  int row  = blockIdx.x * 4 + (threadIdx.x >> 6);
  int lane = threadIdx.x & 63;
  const float4* xr = (const float4*)(x + (size_t)row * 512);
  float4 a = xr[lane];
  float4 b = xr[lane + 64];
  float s = a.x + a.y + a.z + a.w + b.x + b.y + b.z + b.w;
  float q = a.x*a.x + a.y*a.y + a.z*a.z + a.w*a.w
          + b.x*b.x + b.y*b.y + b.z*b.z + b.w*b.w;
  #pragma unroll
  for (int o = 32; o > 0; o >>= 1){
    s += __shfl_xor(s, o);
    q += __shfl_xor(q, o);
  }
  float mu  = s * (1.0f/512.0f);
  float var = q * (1.0f/512.0f) - mu*mu;
  float rs  = rsqrtf(var + 1e-5f);
  int gi = groups[row];
  int idx = ((unsigned)gi < (unsigned)NSUB) ? gi : NSUB;
  const float4* gr = (const float4*)(gammas + (size_t)idx * 512);
  const float4* br = (const float4*)(betas  + (size_t)idx * 512);
  float4 g0 = gr[lane], g1 = gr[lane + 64];
  float4 e0 = br[lane], e1 = br[lane + 64];
  float4 o0, o1;
  o0.x = (a.x - mu)*rs*g0.x + e0.x; o0.y = (a.y - mu)*rs*g0.y + e0.y;
  o0.z = (a.z - mu)*rs*g0.z + e0.z; o0.w = (a.w - mu)*rs*g0.w + e0.w;
  o1.x = (b.x - mu)*rs*g1.x + e1.x; o1.y = (b.y - mu)*rs*g1.y + e1.y;
  o1.z = (b.z - mu)*rs*g1.z + e1.z; o1.w = (b.w - mu)*rs*g1.w + e1.w;
  float4* orow = (float4*)(out + (size_t)row * 512);
  orow[lane]      = o0;
  orow[lane + 64] = o1;
}

__global__ __launch_bounds__(256) void mlp_naive(
    const float* __restrict__ x,
    const float* __restrict__ W1, const float* __restrict__ b1,
    const float* __restrict__ W2, const float* __restrict__ b2,
    const float* __restrict__ W3, const float* __restrict__ b3,
    float* __restrict__ out2){
  __shared__ float xr[512];
  __shared__ float h1[256];
  __shared__ float h2[128];
  int row = blockIdx.x, t = threadIdx.x;
  xr[t]       = x[(size_t)row*512 + t];
  xr[t + 256] = x[(size_t)row*512 + t + 256];
  __syncthreads();
  {
    float s = 0.f;
    for (int k = 0; k < 512; ++k) s += xr[k] * W1[k*256 + t];
    h1[t] = gelu_exact(s + b1[t]);
  }
  __syncthreads();
  if (t < 128){
    float s = 0.f;
    for (int k = 0; k < 256; ++k) s += h1[k] * W2[k*128 + t];
    h2[t] = gelu_exact(s + b2[t]);
  }
  __syncthreads();
  if (t < 16){
    float s = 0.f;
    for (int k = 0; k < 128; ++k) s += h2[k] * W3[k*16 + t];
    out2[(size_t)row*16 + t] = s + b3[t];
  }
}

extern "C" void kernel_launch(void* const* d_in, const int* in_sizes, int n_in,
                              void* d_out, int out_size, void* d_ws, size_t ws_size,
                              hipStream_t stream){
  const float* x      = (const float*)d_in[0];
  const int*   groups = (const int*)d_in[1];
  const float* gammas = (const float*)d_in[2];
  const float* betas  = (const float*)d_in[3];
  const float* W1 = (const float*)d_in[4];
  const float* b1 = (const float*)d_in[5];
  const float* W2 = (const float*)d_in[6];
  const float* b2 = (const float*)d_in[7];
  const float* W3 = (const float*)d_in[8];
  const float* b3 = (const float*)d_in[9];
  float* out  = (float*)d_out;
  const int B = in_sizes[0] / 512;
  float* out2 = out + (size_t)B * 512;

  const size_t ws_need = (size_t)(131072 + 32768 + 2048) * sizeof(unsigned short);
  if (ws_size >= ws_need){
    unsigned short* W1f = (unsigned short*)d_ws;
    unsigned short* W2f = W1f + 131072;
    unsigned short* W3f = W2f + 32768;
    int nconv = 131072 + 32768 + 2048;
    wconv_kernel<<<(nconv + 255)/256, 256, 0, stream>>>(W1, W2, W3, W1f, W2f, W3f);
    fused_kernel<<<B/64, 256, 0, stream>>>(x, groups, gammas, betas,
                                           W1f, b1, W2f, b2, W3f, b3, out, out2);
  } else {
    mlp_naive<<<B, 256, 0, stream>>>(x, W1, b1, W2, b2, W3, b3, out2);
    ln_kernel<<<B/4, 256, 0, stream>>>(x, groups, gammas, betas, out);
  }
}

// Round 4
// 189.210 us; speedup vs baseline: 1.3186x; 1.2212x over previous
//
#include <hip/hip_runtime.h>
#include <hip/hip_bf16.h>
#include <stdint.h>

#define NSUB 16

typedef short  bf16x8 __attribute__((ext_vector_type(8)));
typedef float  f32x4  __attribute__((ext_vector_type(4)));
typedef unsigned int u32x4 __attribute__((ext_vector_type(4)));

__device__ __forceinline__ float gelu_exact(float x){
  return 0.5f * x * (1.0f + erff(x * 0.70710678118654752440f));
}

__device__ __forceinline__ unsigned short f2bf(float f){
  union { float f; uint32_t u; } v; v.f = f;
  uint32_t u = v.u;
  return (unsigned short)((u + 0x7FFFu + ((u >> 16) & 1u)) >> 16);
}

__device__ __forceinline__ unsigned int pk2(float lo, float hi){
  union { __hip_bfloat162 b; unsigned int u; } c;
  c.b = __float22bfloat162_rn(make_float2(lo, hi));
  return c.u;
}

__device__ __forceinline__ bf16x8 as_bf(u32x4 v){
  union { u32x4 u; bf16x8 b; } c; c.u = v; return c.b;
}

__device__ __forceinline__ float bflo(unsigned int u){
  union { unsigned int u; float f; } c; c.u = u << 16; return c.f;
}
__device__ __forceinline__ float bfhi(unsigned int u){
  union { unsigned int u; float f; } c; c.u = u & 0xffff0000u; return c.f;
}

// ---------------- weights -> bf16, MFMA-B-fragment order, into d_ws ----------
// flat = ((ks*NT + nn)*64 + lane)*8 + j ; lane = ((k>>3)&3)*16 + (n&15), j = k&7
__global__ __launch_bounds__(256) void wconv_kernel(
    const float* __restrict__ W1, const float* __restrict__ W2, const float* __restrict__ W3,
    unsigned short* __restrict__ W1f, unsigned short* __restrict__ W2f, unsigned short* __restrict__ W3f){
  int t = blockIdx.x * 256 + threadIdx.x;
  if (t < 131072){                       // W1: K=512, N=256
    int n = t >> 9, k = t & 511;
    int lane = ((k >> 3) & 3) * 16 + (n & 15);
    int idx = (((k >> 5) * 16 + (n >> 4)) * 64 + lane) * 8 + (k & 7);
    W1f[idx] = f2bf(W1[k*256 + n]);
  } else if (t < 131072 + 32768){        // W2: K=256, N=128
    int i = t - 131072; int n = i >> 8, k = i & 255;
    int lane = ((k >> 3) & 3) * 16 + (n & 15);
    int idx = (((k >> 5) * 8 + (n >> 4)) * 64 + lane) * 8 + (k & 7);
    W2f[idx] = f2bf(W2[k*128 + n]);
  } else if (t < 131072 + 32768 + 2048){ // W3: K=128, N=16
    int i = t - (131072 + 32768); int n = i >> 7, k = i & 127;
    int lane = ((k >> 3) & 3) * 16 + n;
    int idx = ((k >> 5) * 64 + lane) * 8 + (k & 7);
    W3f[idx] = f2bf(W3[k*16 + n]);
  }
}

// ---------------- fused LN + 3-GEMM MLP, 32 rows/block ----------------
// 256 thr / 4 waves, grid 4096. LDS 32KB total -> 5 blocks/CU.
// X [32][512]bf16 swizzled (32KB); H1 (16KB) overlays X[0:16K] after GEMM1;
// H2 (8KB) overlays X[16K:24K]. 4 barriers.
__global__ __launch_bounds__(256) void fused_kernel(
    const float* __restrict__ x, const int* __restrict__ groups,
    const float* __restrict__ gammas, const float* __restrict__ betas,
    const unsigned short* __restrict__ W1f, const float* __restrict__ b1,
    const unsigned short* __restrict__ W2f, const float* __restrict__ b2,
    const unsigned short* __restrict__ W3f, const float* __restrict__ b3,
    float* __restrict__ ln_out, float* __restrict__ out2){
  __shared__ __align__(16) uint8_t smem[32768];
  constexpr int OFF_H2 = 16384;

  const int tid  = threadIdx.x;
  const int wave = tid >> 6;
  const int lane = tid & 63;
  const int l15  = lane & 15;
  const int g4   = lane >> 4;
  const int row0 = blockIdx.x * 32;

  // ---- phase 0: stage x -> LDS bf16 (swizzled) + f32 row stats ----
  const int sr  = tid >> 3;           // row 0..31  (8 threads/row)
  const int sc  = tid & 7;            // 8-float column group
  const int swz = (sr & 7) << 4;
  const int wb  = (sc*16) ^ swz;
  uint8_t* xrow = smem + sr*1024;
  const float* xg = x + (size_t)(row0 + sr)*512 + sc*8;

  float s = 0.f, q = 0.f;
  #pragma unroll
  for (int t = 0; t < 8; ++t){
    f32x4 v0 = *(const f32x4*)(xg + t*64);
    f32x4 v1 = *(const f32x4*)(xg + t*64 + 4);
    s += v0.x + v0.y + v0.z + v0.w + v1.x + v1.y + v1.z + v1.w;
    q += v0.x*v0.x + v0.y*v0.y + v0.z*v0.z + v0.w*v0.w
       + v1.x*v1.x + v1.y*v1.y + v1.z*v1.z + v1.w*v1.w;
    u32x4 pw;
    pw.x = pk2(v0.x, v0.y); pw.y = pk2(v0.z, v0.w);
    pw.z = pk2(v1.x, v1.y); pw.w = pk2(v1.z, v1.w);
    *(u32x4*)(xrow + t*128 + wb) = pw;
  }
  s += __shfl_xor(s, 1); s += __shfl_xor(s, 2); s += __shfl_xor(s, 4);
  q += __shfl_xor(q, 1); q += __shfl_xor(q, 2); q += __shfl_xor(q, 4);
  float mu  = s * (1.0f/512.0f);
  float var = q * (1.0f/512.0f) - mu*mu;
  float rs  = rsqrtf(var + 1e-5f);
  float nmr = -mu * rs;
  int gi   = groups[row0 + sr];
  int gidx = ((unsigned)gi < (unsigned)NSUB) ? gi : NSUB;

  // bias preload (L2) — issue early
  float b1v[4], b2v[2], b3v;
  #pragma unroll
  for (int n = 0; n < 4; ++n) b1v[n] = b1[wave*64 + n*16 + l15];
  #pragma unroll
  for (int n = 0; n < 2; ++n) b2v[n] = b2[wave*32 + n*16 + l15];
  b3v = b3[l15];

  // ---- phase 1: LN output (reads back own thread's LDS data; no barrier) ----
  {
    const float* gpr = gammas + (size_t)gidx*512 + sc*8;
    const float* bpr = betas  + (size_t)gidx*512 + sc*8;
    float* op = ln_out + (size_t)(row0 + sr)*512 + sc*8;
    #pragma unroll
    for (int t = 0; t < 8; ++t){
      u32x4 pw = *(const u32x4*)(xrow + t*128 + wb);
      f32x4 g0 = *(const f32x4*)(gpr + t*64);
      f32x4 g1 = *(const f32x4*)(gpr + t*64 + 4);
      f32x4 e0 = *(const f32x4*)(bpr + t*64);
      f32x4 e1 = *(const f32x4*)(bpr + t*64 + 4);
      f32x4 o0, o1;
      o0.x = fmaf(fmaf(bflo(pw.x), rs, nmr), g0.x, e0.x);
      o0.y = fmaf(fmaf(bfhi(pw.x), rs, nmr), g0.y, e0.y);
      o0.z = fmaf(fmaf(bflo(pw.y), rs, nmr), g0.z, e0.z);
      o0.w = fmaf(fmaf(bfhi(pw.y), rs, nmr), g0.w, e0.w);
      o1.x = fmaf(fmaf(bflo(pw.z), rs, nmr), g1.x, e1.x);
      o1.y = fmaf(fmaf(bfhi(pw.z), rs, nmr), g1.y, e1.y);
      o1.z = fmaf(fmaf(bflo(pw.w), rs, nmr), g1.z, e1.z);
      o1.w = fmaf(fmaf(bfhi(pw.w), rs, nmr), g1.w, e1.w);
      *(f32x4*)(op + t*64)     = o0;
      *(f32x4*)(op + t*64 + 4) = o1;
    }
  }

  __syncthreads();   // X fully staged for all threads

  // ---- phase 2: GEMM1 32x256, K=512, zero intra-GEMM barriers ----
  int baseA[2][2];
  #pragma unroll
  for (int m = 0; m < 2; ++m){
    int row = m*16 + l15;
    int sw  = (row & 7) << 4;
    int bse = row*1024 + ((g4*16) ^ (sw & 0x30));
    int kx  = (row >> 2) & 1;
    baseA[m][0] = bse + ((0 ^ kx) << 6);
    baseA[m][1] = bse + ((1 ^ kx) << 6);
  }
  u32x4 braw[2][4];
  #pragma unroll
  for (int n = 0; n < 4; ++n)
    braw[0][n] = *(const u32x4*)(W1f + (size_t)(((wave*4 + n)*64 + lane)*8));
  f32x4 acc1[2][4] = {};
  #pragma unroll
  for (int g = 0; g < 16; ++g){
    if (g < 15){
      #pragma unroll
      for (int n = 0; n < 4; ++n)
        braw[(g+1)&1][n] = *(const u32x4*)(W1f + (size_t)((((g+1)*16 + wave*4 + n)*64 + lane)*8));
    }
    bf16x8 a[2];
    #pragma unroll
    for (int m = 0; m < 2; ++m)
      a[m] = *(const bf16x8*)(smem + baseA[m][g & 1] + (g >> 1)*128);
    #pragma unroll
    for (int m = 0; m < 2; ++m)
      #pragma unroll
      for (int n = 0; n < 4; ++n)
        acc1[m][n] = __builtin_amdgcn_mfma_f32_16x16x32_bf16(a[m], as_bf(braw[g & 1][n]), acc1[m][n], 0, 0, 0);
  }
  __syncthreads();   // all X reads done; H1 may overlay X[0:16K]

  // GEMM2 B prologue
  u32x4 b2raw[2][2];
  #pragma unroll
  for (int n = 0; n < 2; ++n)
    b2raw[0][n] = *(const u32x4*)(W2f + (size_t)(((wave*2 + n)*64 + lane)*8));

  // ---- epilogue 1: bias + GELU -> H1 bf16 swizzled at smem[0:16K] ----
  #pragma unroll
  for (int n = 0; n < 4; ++n){
    #pragma unroll
    for (int m = 0; m < 2; ++m){
      #pragma unroll
      for (int r = 0; r < 4; ++r){
        int row = m*16 + g4*4 + r;
        int col = wave*64 + n*16 + l15;
        float v = gelu_exact(acc1[m][n][r] + b1v[n]);
        *(unsigned short*)(smem + row*512 + ((col*2) ^ ((row & 7) << 4))) = f2bf(v);
      }
    }
  }
  __syncthreads();   // H1 ready

  // ---- phase 3: GEMM2 32x128, K=256 ----
  int baseH[2][2];
  #pragma unroll
  for (int m = 0; m < 2; ++m){
    int row = m*16 + l15;
    int sw  = (row & 7) << 4;
    int bse = row*512 + ((g4*16) ^ (sw & 0x30));
    int kx  = (row >> 2) & 1;
    baseH[m][0] = bse + ((0 ^ kx) << 6);
    baseH[m][1] = bse + ((1 ^ kx) << 6);
  }
  f32x4 acc2[2][2] = {};
  #pragma unroll
  for (int g = 0; g < 8; ++g){
    if (g < 7){
      #pragma unroll
      for (int n = 0; n < 2; ++n)
        b2raw[(g+1)&1][n] = *(const u32x4*)(W2f + (size_t)((((g+1)*8 + wave*2 + n)*64 + lane)*8));
    }
    bf16x8 a[2];
    #pragma unroll
    for (int m = 0; m < 2; ++m)
      a[m] = *(const bf16x8*)(smem + baseH[m][g & 1] + (g >> 1)*128);
    #pragma unroll
    for (int m = 0; m < 2; ++m)
      #pragma unroll
      for (int n = 0; n < 2; ++n)
        acc2[m][n] = __builtin_amdgcn_mfma_f32_16x16x32_bf16(a[m], as_bf(b2raw[g & 1][n]), acc2[m][n], 0, 0, 0);
  }

  // W3 fragment prefetch
  u32x4 b3raw[4];
  #pragma unroll
  for (int ks = 0; ks < 4; ++ks)
    b3raw[ks] = *(const u32x4*)(W3f + (size_t)((ks*64 + lane)*8));

  // ---- epilogue 2: bias + GELU -> H2 bf16 swizzled at smem[16K:24K] ----
  // (H2 region disjoint from H1; its X contents are dead past barrier 2)
  #pragma unroll
  for (int n = 0; n < 2; ++n){
    #pragma unroll
    for (int m = 0; m < 2; ++m){
      #pragma unroll
      for (int r = 0; r < 4; ++r){
        int row = m*16 + g4*4 + r;
        int col = wave*32 + n*16 + l15;
        float v = gelu_exact(acc2[m][n][r] + b2v[n]);
        *(unsigned short*)(smem + OFF_H2 + row*256 + ((col*2) ^ ((row & 7) << 4))) = f2bf(v);
      }
    }
  }
  __syncthreads();   // H2 ready

  // ---- phase 4: GEMM3 32x16, K=128; waves 0,1 own rows 0..15 / 16..31 ----
  int baseG[2];
  {
    int row = (wave & 1)*16 + l15;
    int sw  = (row & 7) << 4;
    int bse = OFF_H2 + row*256 + ((g4*16) ^ (sw & 0x30));
    int kx  = (row >> 2) & 1;
    baseG[0] = bse + ((0 ^ kx) << 6);
    baseG[1] = bse + ((1 ^ kx) << 6);
  }
  f32x4 acc3 = {};
  #pragma unroll
  for (int ks = 0; ks < 4; ++ks){
    bf16x8 a = *(const bf16x8*)(smem + baseG[ks & 1] + (ks >> 1)*128);
    acc3 = __builtin_amdgcn_mfma_f32_16x16x32_bf16(a, as_bf(b3raw[ks]), acc3, 0, 0, 0);
  }
  if (wave < 2){
    #pragma unroll
    for (int r = 0; r < 4; ++r){
      int grow = row0 + wave*16 + g4*4 + r;
      out2[(size_t)grow*16 + l15] = acc3[r] + b3v;
    }
  }
}

// ---------------- fallback path (ws too small): naive MLP + standalone LN ----------------
__global__ __launch_bounds__(256) void ln_kernel(
    const float* __restrict__ x, const int* __restrict__ groups,
    const float* __restrict__ gammas, const float* __restrict__ betas,
    float* __restrict__ out){
  int row  = blockIdx.x * 4 + (threadIdx.x >> 6);
  int lane = threadIdx.x & 63;
  const float4* xr = (const float4*)(x + (size_t)row * 512);
  float4 a = xr[lane];
  float4 b = xr[lane + 64];
  float s = a.x + a.y + a.z + a.w + b.x + b.y + b.z + b.w;
  float q = a.x*a.x + a.y*a.y + a.z*a.z + a.w*a.w
          + b.x*b.x + b.y*b.y + b.z*b.z + b.w*b.w;
  #pragma unroll
  for (int o = 32; o > 0; o >>= 1){
    s += __shfl_xor(s, o);
    q += __shfl_xor(q, o);
  }
  float mu  = s * (1.0f/512.0f);
  float var = q * (1.0f/512.0f) - mu*mu;
  float rs  = rsqrtf(var + 1e-5f);
  int gi = groups[row];
  int idx = ((unsigned)gi < (unsigned)NSUB) ? gi : NSUB;
  const float4* gr = (const float4*)(gammas + (size_t)idx * 512);
  const float4* br = (const float4*)(betas  + (size_t)idx * 512);
  float4 g0 = gr[lane], g1 = gr[lane + 64];
  float4 e0 = br[lane], e1 = br[lane + 64];
  float4 o0, o1;
  o0.x = (a.x - mu)*rs*g0.x + e0.x; o0.y = (a.y - mu)*rs*g0.y + e0.y;
  o0.z = (a.z - mu)*rs*g0.z + e0.z; o0.w = (a.w - mu)*rs*g0.w + e0.w;
  o1.x = (b.x - mu)*rs*g1.x + e1.x; o1.y = (b.y - mu)*rs*g1.y + e1.y;
  o1.z = (b.z - mu)*rs*g1.z + e1.z; o1.w = (b.w - mu)*rs*g1.w + e1.w;
  float4* orow = (float4*)(out + (size_t)row * 512);
  orow[lane]      = o0;
  orow[lane + 64] = o1;
}

__global__ __launch_bounds__(256) void mlp_naive(
    const float* __restrict__ x,
    const float* __restrict__ W1, const float* __restrict__ b1,
    const float* __restrict__ W2, const float* __restrict__ b2,
    const float* __restrict__ W3, const float* __restrict__ b3,
    float* __restrict__ out2){
  __shared__ float xr[512];
  __shared__ float h1[256];
  __shared__ float h2[128];
  int row = blockIdx.x, t = threadIdx.x;
  xr[t]       = x[(size_t)row*512 + t];
  xr[t + 256] = x[(size_t)row*512 + t + 256];
  __syncthreads();
  {
    float s = 0.f;
    for (int k = 0; k < 512; ++k) s += xr[k] * W1[k*256 + t];
    h1[t] = gelu_exact(s + b1[t]);
  }
  __syncthreads();
  if (t < 128){
    float s = 0.f;
    for (int k = 0; k < 256; ++k) s += h1[k] * W2[k*128 + t];
    h2[t] = gelu_exact(s + b2[t]);
  }
  __syncthreads();
  if (t < 16){
    float s = 0.f;
    for (int k = 0; k < 128; ++k) s += h2[k] * W3[k*16 + t];
    out2[(size_t)row*16 + t] = s + b3[t];
  }
}

extern "C" void kernel_launch(void* const* d_in, const int* in_sizes, int n_in,
                              void* d_out, int out_size, void* d_ws, size_t ws_size,
                              hipStream_t stream){
  const float* x      = (const float*)d_in[0];
  const int*   groups = (const int*)d_in[1];
  const float* gammas = (const float*)d_in[2];
  const float* betas  = (const float*)d_in[3];
  const float* W1 = (const float*)d_in[4];
  const float* b1 = (const float*)d_in[5];
  const float* W2 = (const float*)d_in[6];
  const float* b2 = (const float*)d_in[7];
  const float* W3 = (const float*)d_in[8];
  const float* b3 = (const float*)d_in[9];
  float* out  = (float*)d_out;
  const int B = in_sizes[0] / 512;
  float* out2 = out + (size_t)B * 512;

  const size_t ws_need = (size_t)(131072 + 32768 + 2048) * sizeof(unsigned short);
  if (ws_size >= ws_need){
    unsigned short* W1f = (unsigned short*)d_ws;
    unsigned short* W2f = W1f + 131072;
    unsigned short* W3f = W2f + 32768;
    int nconv = 131072 + 32768 + 2048;
    wconv_kernel<<<(nconv + 255)/256, 256, 0, stream>>>(W1, W2, W3, W1f, W2f, W3f);
    fused_kernel<<<B/32, 256, 0, stream>>>(x, groups, gammas, betas,
                                           W1f, b1, W2f, b2, W3f, b3, out, out2);
  } else {
    mlp_naive<<<B, 256, 0, stream>>>(x, W1, b1, W2, b2, W3, b3, out2);
    ln_kernel<<<B/4, 256, 0, stream>>>(x, groups, gammas, betas, out);
  }
}

// Round 5
// 188.133 us; speedup vs baseline: 1.3261x; 1.0057x over previous
//
#include <hip/hip_runtime.h>
#include <hip/hip_bf16.h>
#include <stdint.h>

#define NSUB 16

typedef short  bf16x8 __attribute__((ext_vector_type(8)));
typedef float  f32x4  __attribute__((ext_vector_type(4)));
typedef unsigned int u32x4 __attribute__((ext_vector_type(4)));

__device__ __forceinline__ float gelu_exact(float x){
  return 0.5f * x * (1.0f + erff(x * 0.70710678118654752440f));
}

__device__ __forceinline__ unsigned short f2bf(float f){
  union { float f; uint32_t u; } v; v.f = f;
  uint32_t u = v.u;
  return (unsigned short)((u + 0x7FFFu + ((u >> 16) & 1u)) >> 16);
}

__device__ __forceinline__ unsigned int pk2(float lo, float hi){
  union { __hip_bfloat162 b; unsigned int u; } c;
  c.b = __float22bfloat162_rn(make_float2(lo, hi));
  return c.u;
}

__device__ __forceinline__ bf16x8 as_bf(u32x4 v){
  union { u32x4 u; bf16x8 b; } c; c.u = v; return c.b;
}

__device__ __forceinline__ float bflo(unsigned int u){
  union { unsigned int u; float f; } c; c.u = u << 16; return c.f;
}
__device__ __forceinline__ float bfhi(unsigned int u){
  union { unsigned int u; float f; } c; c.u = u & 0xffff0000u; return c.f;
}

// ---------------- weights + gamma/beta -> bf16 into d_ws ----------
// W*f in MFMA-B-fragment order: flat = ((ks*NT + nn)*64 + lane)*8 + j,
// lane = ((k>>3)&3)*16 + (n&15), j = k&7.  gbf_g/gbf_b: [17][512] bf16 linear.
__global__ __launch_bounds__(256) void wconv_kernel(
    const float* __restrict__ W1, const float* __restrict__ W2, const float* __restrict__ W3,
    const float* __restrict__ gammas, const float* __restrict__ betas,
    unsigned short* __restrict__ W1f, unsigned short* __restrict__ W2f,
    unsigned short* __restrict__ W3f, unsigned short* __restrict__ Gf,
    unsigned short* __restrict__ Bf){
  int t = blockIdx.x * 256 + threadIdx.x;
  if (t < 131072){                       // W1: K=512, N=256
    int n = t >> 9, k = t & 511;
    int lane = ((k >> 3) & 3) * 16 + (n & 15);
    int idx = (((k >> 5) * 16 + (n >> 4)) * 64 + lane) * 8 + (k & 7);
    W1f[idx] = f2bf(W1[k*256 + n]);
  } else if (t < 163840){                // W2: K=256, N=128
    int i = t - 131072; int n = i >> 8, k = i & 255;
    int lane = ((k >> 3) & 3) * 16 + (n & 15);
    int idx = (((k >> 5) * 8 + (n >> 4)) * 64 + lane) * 8 + (k & 7);
    W2f[idx] = f2bf(W2[k*128 + n]);
  } else if (t < 165888){                // W3: K=128, N=16
    int i = t - 163840; int n = i >> 7, k = i & 127;
    int lane = ((k >> 3) & 3) * 16 + n;
    int idx = ((k >> 5) * 64 + lane) * 8 + (k & 7);
    W3f[idx] = f2bf(W3[k*16 + n]);
  } else if (t < 174592){                // gamma: 17*512
    int i = t - 165888;
    Gf[i] = f2bf(gammas[i]);
  } else if (t < 183296){                // beta
    int i = t - 174592;
    Bf[i] = f2bf(betas[i]);
  }
}

// ---------------- fused LN + 3-GEMM MLP, 32 rows/block ----------------
// 256 thr / 4 waves, grid 4096, LDS 32KB. LN interleaved into GEMM1 (T14-style:
// issue-early/consume-late), W prefetch rings, NT stores for outputs.
__global__ __launch_bounds__(256, 4) void fused_kernel(
    const float* __restrict__ x, const int* __restrict__ groups,
    const unsigned short* __restrict__ Gf, const unsigned short* __restrict__ Bf,
    const unsigned short* __restrict__ W1f, const float* __restrict__ b1,
    const unsigned short* __restrict__ W2f, const float* __restrict__ b2,
    const unsigned short* __restrict__ W3f, const float* __restrict__ b3,
    float* __restrict__ ln_out, float* __restrict__ out2){
  __shared__ __align__(16) uint8_t smem[32768];
  constexpr int OFF_H2 = 16384;

  const int tid  = threadIdx.x;
  const int wave = tid >> 6;
  const int lane = tid & 63;
  const int l15  = lane & 15;
  const int g4   = lane >> 4;
  const int row0 = blockIdx.x * 32;

  // ---- phase 0: stage x -> LDS bf16 (swizzled) + f32 row stats ----
  const int sr  = tid >> 3;           // row 0..31  (8 threads/row)
  const int sc  = tid & 7;            // 8-float column group
  const int swz = (sr & 7) << 4;
  const int wb  = (sc*16) ^ swz;
  uint8_t* xrow = smem + sr*1024;
  const float* xg = x + (size_t)(row0 + sr)*512 + sc*8;

  int gi   = groups[row0 + sr];
  int gidx = ((unsigned)gi < (unsigned)NSUB) ? gi : NSUB;

  float s = 0.f, q = 0.f;
  #pragma unroll
  for (int t = 0; t < 8; ++t){
    f32x4 v0 = *(const f32x4*)(xg + t*64);
    f32x4 v1 = *(const f32x4*)(xg + t*64 + 4);
    s += v0.x + v0.y + v0.z + v0.w + v1.x + v1.y + v1.z + v1.w;
    q += v0.x*v0.x + v0.y*v0.y + v0.z*v0.z + v0.w*v0.w
       + v1.x*v1.x + v1.y*v1.y + v1.z*v1.z + v1.w*v1.w;
    u32x4 pw;
    pw.x = pk2(v0.x, v0.y); pw.y = pk2(v0.z, v0.w);
    pw.z = pk2(v1.x, v1.y); pw.w = pk2(v1.z, v1.w);
    *(u32x4*)(xrow + t*128 + wb) = pw;
  }
  s += __shfl_xor(s, 1); s += __shfl_xor(s, 2); s += __shfl_xor(s, 4);
  q += __shfl_xor(q, 1); q += __shfl_xor(q, 2); q += __shfl_xor(q, 4);
  float mu  = s * (1.0f/512.0f);
  float var = q * (1.0f/512.0f) - mu*mu;
  float rs  = rsqrtf(var + 1e-5f);
  float nmr = -mu * rs;

  // bias preload (L2) — early
  float b1v[4], b2v[2], b3v;
  #pragma unroll
  for (int n = 0; n < 4; ++n) b1v[n] = b1[wave*64 + n*16 + l15];
  #pragma unroll
  for (int n = 0; n < 2; ++n) b2v[n] = b2[wave*32 + n*16 + l15];
  b3v = b3[l15];

  // LN pointers + chunk-0 pipeline prologue (own-thread LDS + L2, pre-barrier)
  const unsigned short* gam = Gf + (size_t)gidx*512 + sc*8;
  const unsigned short* bet = Bf + (size_t)gidx*512 + sc*8;
  float* op = ln_out + (size_t)(row0 + sr)*512 + sc*8;
  u32x4 pwc = *(const u32x4*)(xrow + wb);
  u32x4 ggc = *(const u32x4*)gam;
  u32x4 bbc = *(const u32x4*)bet;

  // W1 ring-2 prologue (independent of LDS — issue before barrier)
  u32x4 braw[2][4];
  #pragma unroll
  for (int n = 0; n < 4; ++n)
    braw[0][n] = *(const u32x4*)(W1f + (size_t)(((wave*4 + n)*64 + lane)*8));

  // GEMM1 A-fragment base addresses (swizzle folded into two bases)
  int baseA[2][2];
  #pragma unroll
  for (int m = 0; m < 2; ++m){
    int row = m*16 + l15;
    int sw  = (row & 7) << 4;
    int bse = row*1024 + ((g4*16) ^ (sw & 0x30));
    int kx  = (row >> 2) & 1;
    baseA[m][0] = bse + ((0 ^ kx) << 6);
    baseA[m][1] = bse + ((1 ^ kx) << 6);
  }

  __syncthreads();   // X fully staged

  // ---- GEMM1 (32x256, K=512) with LN interleaved at odd steps ----
  f32x4 acc1[2][4] = {};
  #pragma unroll
  for (int g = 0; g < 16; ++g){
    if (g < 15){
      #pragma unroll
      for (int n = 0; n < 4; ++n)
        braw[(g+1)&1][n] = *(const u32x4*)(W1f + (size_t)((((g+1)*16 + wave*4 + n)*64 + lane)*8));
    }
    bf16x8 a[2];
    #pragma unroll
    for (int m = 0; m < 2; ++m)
      a[m] = *(const bf16x8*)(smem + baseA[m][g & 1] + (g >> 1)*128);
    if (g & 1){
      const int c = g >> 1;      // LN chunk 0..7
      u32x4 pwn = pwc, ggn = ggc, bbn = bbc;
      if (c < 7){                // issue next chunk's loads first (latency cover)
        pwn = *(const u32x4*)(xrow + (c+1)*128 + wb);
        ggn = *(const u32x4*)(gam + (c+1)*64);
        bbn = *(const u32x4*)(bet + (c+1)*64);
      }
      f32x4 o0, o1;
      o0.x = fmaf(fmaf(bflo(pwc.x), rs, nmr), bflo(ggc.x), bflo(bbc.x));
      o0.y = fmaf(fmaf(bfhi(pwc.x), rs, nmr), bfhi(ggc.x), bfhi(bbc.x));
      o0.z = fmaf(fmaf(bflo(pwc.y), rs, nmr), bflo(ggc.y), bflo(bbc.y));
      o0.w = fmaf(fmaf(bfhi(pwc.y), rs, nmr), bfhi(ggc.y), bfhi(bbc.y));
      o1.x = fmaf(fmaf(bflo(pwc.z), rs, nmr), bflo(ggc.z), bflo(bbc.z));
      o1.y = fmaf(fmaf(bfhi(pwc.z), rs, nmr), bfhi(ggc.z), bfhi(bbc.z));
      o1.z = fmaf(fmaf(bflo(pwc.w), rs, nmr), bflo(ggc.w), bflo(bbc.w));
      o1.w = fmaf(fmaf(bfhi(pwc.w), rs, nmr), bfhi(ggc.w), bfhi(bbc.w));
      __builtin_nontemporal_store(o0, (f32x4*)(op + c*64));
      __builtin_nontemporal_store(o1, (f32x4*)(op + c*64 + 4));
      pwc = pwn; ggc = ggn; bbc = bbn;
    }
    #pragma unroll
    for (int m = 0; m < 2; ++m)
      #pragma unroll
      for (int n = 0; n < 4; ++n)
        acc1[m][n] = __builtin_amdgcn_mfma_f32_16x16x32_bf16(a[m], as_bf(braw[g & 1][n]), acc1[m][n], 0, 0, 0);
  }

  // GEMM2 ring-4 prologue: issue 3 steps (covered by epilogue-1's erf VALU)
  u32x4 b2raw[4][2];
  #pragma unroll
  for (int p = 0; p < 3; ++p)
    #pragma unroll
    for (int n = 0; n < 2; ++n)
      b2raw[p][n] = *(const u32x4*)(W2f + (size_t)(((p*8 + wave*2 + n)*64 + lane)*8));

  __syncthreads();   // all X reads done (incl. LN); H1 may overlay X[0:16K]

  // ---- epilogue 1: bias + GELU -> H1 bf16 swizzled at smem[0:16K] ----
  #pragma unroll
  for (int n = 0; n < 4; ++n){
    #pragma unroll
    for (int m = 0; m < 2; ++m){
      #pragma unroll
      for (int r = 0; r < 4; ++r){
        int row = m*16 + g4*4 + r;
        int col = wave*64 + n*16 + l15;
        float v = gelu_exact(acc1[m][n][r] + b1v[n]);
        *(unsigned short*)(smem + row*512 + ((col*2) ^ ((row & 7) << 4))) = f2bf(v);
      }
    }
  }
  __syncthreads();   // H1 ready

  // ---- GEMM2 (32x128, K=256), ring-4 W prefetch 3 ahead ----
  int baseH[2][2];
  #pragma unroll
  for (int m = 0; m < 2; ++m){
    int row = m*16 + l15;
    int sw  = (row & 7) << 4;
    int bse = row*512 + ((g4*16) ^ (sw & 0x30));
    int kx  = (row >> 2) & 1;
    baseH[m][0] = bse + ((0 ^ kx) << 6);
    baseH[m][1] = bse + ((1 ^ kx) << 6);
  }
  f32x4 acc2[2][2] = {};
  #pragma unroll
  for (int g = 0; g < 8; ++g){
    if (g < 5){
      #pragma unroll
      for (int n = 0; n < 2; ++n)
        b2raw[(g+3)&3][n] = *(const u32x4*)(W2f + (size_t)((((g+3)*8 + wave*2 + n)*64 + lane)*8));
    }
    bf16x8 a[2];
    #pragma unroll
    for (int m = 0; m < 2; ++m)
      a[m] = *(const bf16x8*)(smem + baseH[m][g & 1] + (g >> 1)*128);
    #pragma unroll
    for (int m = 0; m < 2; ++m)
      #pragma unroll
      for (int n = 0; n < 2; ++n)
        acc2[m][n] = __builtin_amdgcn_mfma_f32_16x16x32_bf16(a[m], as_bf(b2raw[g & 3][n]), acc2[m][n], 0, 0, 0);
  }

  // W3 fragment prefetch (covered by epilogue-2 VALU)
  u32x4 b3raw[4];
  #pragma unroll
  for (int ks = 0; ks < 4; ++ks)
    b3raw[ks] = *(const u32x4*)(W3f + (size_t)((ks*64 + lane)*8));

  // ---- epilogue 2: bias + GELU -> H2 bf16 swizzled at smem[16K:24K] ----
  #pragma unroll
  for (int n = 0; n < 2; ++n){
    #pragma unroll
    for (int m = 0; m < 2; ++m){
      #pragma unroll
      for (int r = 0; r < 4; ++r){
        int row = m*16 + g4*4 + r;
        int col = wave*32 + n*16 + l15;
        float v = gelu_exact(acc2[m][n][r] + b2v[n]);
        *(unsigned short*)(smem + OFF_H2 + row*256 + ((col*2) ^ ((row & 7) << 4))) = f2bf(v);
      }
    }
  }
  __syncthreads();   // H2 ready

  // ---- GEMM3 (32x16, K=128); waves 0,1 own rows 0..15 / 16..31 ----
  int baseG[2];
  {
    int row = (wave & 1)*16 + l15;
    int sw  = (row & 7) << 4;
    int bse = OFF_H2 + row*256 + ((g4*16) ^ (sw & 0x30));
    int kx  = (row >> 2) & 1;
    baseG[0] = bse + ((0 ^ kx) << 6);
    baseG[1] = bse + ((1 ^ kx) << 6);
  }
  f32x4 acc3 = {};
  #pragma unroll
  for (int ks = 0; ks < 4; ++ks){
    bf16x8 a = *(const bf16x8*)(smem + baseG[ks & 1] + (ks >> 1)*128);
    acc3 = __builtin_amdgcn_mfma_f32_16x16x32_bf16(a, as_bf(b3raw[ks]), acc3, 0, 0, 0);
  }
  if (wave < 2){
    #pragma unroll
    for (int r = 0; r < 4; ++r){
      int grow = row0 + wave*16 + g4*4 + r;
      __builtin_nontemporal_store(acc3[r] + b3v, &out2[(size_t)grow*16 + l15]);
    }
  }
}

// ---------------- fallback path (ws too small): naive MLP + standalone LN ----------------
__global__ __launch_bounds__(256) void ln_kernel(
    const float* __restrict__ x, const int* __restrict__ groups,
    const float* __restrict__ gammas, const float* __restrict__ betas,
    float* __restrict__ out){
  int row  = blockIdx.x * 4 + (threadIdx.x >> 6);
  int lane = threadIdx.x & 63;
  const float4* xr = (const float4*)(x + (size_t)row * 512);
  float4 a = xr[lane];
  float4 b = xr[lane + 64];
  float s = a.x + a.y + a.z + a.w + b.x + b.y + b.z + b.w;
  float q = a.x*a.x + a.y*a.y + a.z*a.z + a.w*a.w
          + b.x*b.x + b.y*b.y + b.z*b.z + b.w*b.w;
  #pragma unroll
  for (int o = 32; o > 0; o >>= 1){
    s += __shfl_xor(s, o);
    q += __shfl_xor(q, o);
  }
  float mu  = s * (1.0f/512.0f);
  float var = q * (1.0f/512.0f) - mu*mu;
  float rsq = rsqrtf(var + 1e-5f);
  int gi = groups[row];
  int idx = ((unsigned)gi < (unsigned)NSUB) ? gi : NSUB;
  const float4* gr = (const float4*)(gammas + (size_t)idx * 512);
  const float4* br = (const float4*)(betas  + (size_t)idx * 512);
  float4 g0 = gr[lane], g1 = gr[lane + 64];
  float4 e0 = br[lane], e1 = br[lane + 64];
  float4 o0, o1;
  o0.x = (a.x - mu)*rsq*g0.x + e0.x; o0.y = (a.y - mu)*rsq*g0.y + e0.y;
  o0.z = (a.z - mu)*rsq*g0.z + e0.z; o0.w = (a.w - mu)*rsq*g0.w + e0.w;
  o1.x = (b.x - mu)*rsq*g1.x + e1.x; o1.y = (b.y - mu)*rsq*g1.y + e1.y;
  o1.z = (b.z - mu)*rsq*g1.z + e1.z; o1.w = (b.w - mu)*rsq*g1.w + e1.w;
  float4* orow = (float4*)(out + (size_t)row * 512);
  orow[lane]      = o0;
  orow[lane + 64] = o1;
}

__global__ __launch_bounds__(256) void mlp_naive(
    const float* __restrict__ x,
    const float* __restrict__ W1, const float* __restrict__ b1,
    const float* __restrict__ W2, const float* __restrict__ b2,
    const float* __restrict__ W3, const float* __restrict__ b3,
    float* __restrict__ out2){
  __shared__ float xr[512];
  __shared__ float h1[256];
  __shared__ float h2[128];
  int row = blockIdx.x, t = threadIdx.x;
  xr[t]       = x[(size_t)row*512 + t];
  xr[t + 256] = x[(size_t)row*512 + t + 256];
  __syncthreads();
  {
    float s = 0.f;
    for (int k = 0; k < 512; ++k) s += xr[k] * W1[k*256 + t];
    h1[t] = gelu_exact(s + b1[t]);
  }
  __syncthreads();
  if (t < 128){
    float s = 0.f;
    for (int k = 0; k < 256; ++k) s += h1[k] * W2[k*128 + t];
    h2[t] = gelu_exact(s + b2[t]);
  }
  __syncthreads();
  if (t < 16){
    float s = 0.f;
    for (int k = 0; k < 128; ++k) s += h2[k] * W3[k*16 + t];
    out2[(size_t)row*16 + t] = s + b3[t];
  }
}

extern "C" void kernel_launch(void* const* d_in, const int* in_sizes, int n_in,
                              void* d_out, int out_size, void* d_ws, size_t ws_size,
                              hipStream_t stream){
  const float* x      = (const float*)d_in[0];
  const int*   groups = (const int*)d_in[1];
  const float* gammas = (const float*)d_in[2];
  const float* betas  = (const float*)d_in[3];
  const float* W1 = (const float*)d_in[4];
  const float* b1 = (const float*)d_in[5];
  const float* W2 = (const float*)d_in[6];
  const float* b2 = (const float*)d_in[7];
  const float* W3 = (const float*)d_in[8];
  const float* b3 = (const float*)d_in[9];
  float* out  = (float*)d_out;
  const int B = in_sizes[0] / 512;
  float* out2 = out + (size_t)B * 512;

  // ws layout (u16): W1f 131072 | W2f 32768 | W3f 2048 | Gf 8704 | Bf 8704
  const int n_u16 = 131072 + 32768 + 2048 + 8704 + 8704;
  const size_t ws_need = (size_t)n_u16 * sizeof(unsigned short);
  if (ws_size >= ws_need){
    unsigned short* W1f = (unsigned short*)d_ws;
    unsigned short* W2f = W1f + 131072;
    unsigned short* W3f = W2f + 32768;
    unsigned short* Gf  = W3f + 2048;
    unsigned short* Bf  = Gf + 8704;
    wconv_kernel<<<(n_u16 + 255)/256, 256, 0, stream>>>(W1, W2, W3, gammas, betas,
                                                        W1f, W2f, W3f, Gf, Bf);
    fused_kernel<<<B/32, 256, 0, stream>>>(x, groups, Gf, Bf,
                                           W1f, b1, W2f, b2, W3f, b3, out, out2);
  } else {
    mlp_naive<<<B, 256, 0, stream>>>(x, W1, b1, W2, b2, W3, b3, out2);
    ln_kernel<<<B/4, 256, 0, stream>>>(x, groups, gammas, betas, out);
  }
}